// Round 1
// baseline (553.310 us; speedup 1.0000x reference)
//
#include <hip/hip_runtime.h>
#include <hip/hip_bf16.h>

#define TT 256

typedef __attribute__((ext_vector_type(8))) short bf16x8;
typedef __attribute__((ext_vector_type(4))) float f32x4;

__device__ __forceinline__ unsigned short f2b(float f) {
    union { float f; unsigned u; } v; v.f = f;
    unsigned r = v.u + 0x7FFFu + ((v.u >> 16) & 1u);
    return (unsigned short)(r >> 16);
}
__device__ __forceinline__ float b2f(unsigned short h) {
    union { unsigned u; float f; } v; v.u = ((unsigned)h) << 16;
    return v.f;
}
__device__ __forceinline__ ushort2 pk2(float a, float b) {
    __hip_bfloat162 h = __float22bfloat162_rn(float2{a, b});
    union { __hip_bfloat162 h; ushort2 u; } v; v.h = h; return v.u;
}

// B-layout per (s,t): 16-batch x K shorts, addr(b,k) = (k>>3)*128 + b*8 + (k&7).
// B-frag kc = one b128 at kc*512 + rdo (rdo = quad*128 + l15*8);
// D-tile mt write = ushort4 at wro + mt*256.

// ---------------- a1 = bf16(x @ Wx1), full-GPU parallel precompute ----------
// Stored in rnn4's C-operand fragment order so the serial kernel initializes
// its L1 accumulator by a single coalesced 32B read per lane:
//   a1[(s*T+t)*2048 + (mt>>2)*1024 + (quad*16 + b)*16 + (mt&3)*4 + j]
// holds value (b, h = mt*16 + quad*4 + j). Bias b1 is NOT included (kept f32
// in rnn4) so the only new rounding vs the old path is bf16(x@Wx1).
// Replaces cvt_tile4; grid 256 = 32 s x 8 tg, wave wv handles 8 t's.
__global__ __launch_bounds__(256) void xw1(const float* __restrict__ x,
                                           const float* __restrict__ Wx1,
                                           unsigned short* __restrict__ a1) {
    const int s = blockIdx.x >> 3;
    const int tg = blockIdx.x & 7;
    const int wv = threadIdx.x >> 6;
    const int lane = threadIdx.x & 63;
    const int l15 = lane & 15;
    const int quad = lane >> 4;
    const int t0 = tg * 32 + wv * 8;

    // Wx1 A-frags (same convention as rnn4's LOADW): wf[kc*8+mt][j] =
    // Wx1[(kc*32 + quad*8 + j)*128 + mt*16 + l15]
    bf16x8 wf[16];
#pragma unroll
    for (int kc = 0; kc < 2; ++kc)
#pragma unroll
        for (int mt = 0; mt < 8; ++mt)
#pragma unroll
            for (int j = 0; j < 8; ++j)
                wf[kc * 8 + mt][j] =
                    (short)f2b(Wx1[(kc * 32 + quad * 8 + j) * 128 + mt * 16 + l15]);

    const float* xr = x + ((size_t)(s * 16 + l15) * TT + t0) * 64 + quad * 8;
    unsigned short* ob = a1 + ((size_t)s * TT + t0) * 2048 + (quad * 16 + l15) * 16;

#pragma unroll 2
    for (int i = 0; i < 8; ++i) {
        bf16x8 xf[2];  // x B-frags: (b=l15, k = kx*32 + quad*8 + j)
#pragma unroll
        for (int kx = 0; kx < 2; ++kx) {
            float4 va = *reinterpret_cast<const float4*>(xr + i * 64 + kx * 32);
            float4 vb = *reinterpret_cast<const float4*>(xr + i * 64 + kx * 32 + 4);
            ushort2 p0 = pk2(va.x, va.y), p1 = pk2(va.z, va.w);
            ushort2 p2 = pk2(vb.x, vb.y), p3 = pk2(vb.z, vb.w);
            bf16x8 r;
            r[0] = p0.x; r[1] = p0.y; r[2] = p1.x; r[3] = p1.y;
            r[4] = p2.x; r[5] = p2.y; r[6] = p3.x; r[7] = p3.y;
            xf[kx] = r;
        }
#pragma unroll
        for (int mt = 0; mt < 8; ++mt) {
            f32x4 z = {0.f, 0.f, 0.f, 0.f};
            f32x4 acc = __builtin_amdgcn_mfma_f32_16x16x32_bf16(wf[mt], xf[0], z, 0, 0, 0);
            acc = __builtin_amdgcn_mfma_f32_16x16x32_bf16(wf[8 + mt], xf[1], acc, 0, 0, 0);
            ushort2 lo = pk2(acc[0], acc[1]), hi = pk2(acc[2], acc[3]);
            ushort4 o; o.x = lo.x; o.y = lo.y; o.z = hi.x; o.w = hi.y;
            *reinterpret_cast<ushort4*>(ob + (size_t)i * 2048 + (mt >> 2) * 1024 +
                                        (mt & 3) * 4) = o;
        }
    }
}

// ---------------- 4-layer skewed fused RNN, wave-specialized ----------------
// EXACT round-15/17 winner hot loop for w2-7 (untouched). 8 waves: w0,w1 =
// L1+L4; w2-5 = L2; w6,7 = L3. Changes this round, confined to w0/w1:
//   - L1 x-MFMAs replaced by a1 C-init (drops Wx1 wreg[16..23] + x wreg[36..39])
//   - L4's global H4 store replaced by a fused dense accumulate (dacc), with
//     2 JIT float4 Wd loads issued at STEP top (~500cy before consumption)
//   - epilogue: LDS-reduce dacc (8 lanes per batch) -> out[s*16+b] directly
// w2-5 keep s_setprio(1) (heavy waves: narrow barrier-arrival spread).
__global__ __launch_bounds__(512) __attribute__((amdgpu_waves_per_eu(2, 2))) void rnn4(
    const unsigned short* __restrict__ A1,
    const float* __restrict__ Wh1, const float* __restrict__ b1,
    const float* __restrict__ Wx2, const float* __restrict__ Wh2, const float* __restrict__ b2,
    const float* __restrict__ Wx3, const float* __restrict__ Wh3, const float* __restrict__ b3,
    const float* __restrict__ Wx4, const float* __restrict__ Wh4, const float* __restrict__ b4,
    const float* __restrict__ Wd, const float* __restrict__ bd,
    float* __restrict__ out) {
    const int tid = threadIdx.x;
    const int s = blockIdx.x;
    const int w = tid >> 6;
    const int lane = tid & 63;
    const int l15 = lane & 15;
    const int quad = lane >> 4;
    const int rdo = quad * 128 + l15 * 8;

    // LDS: h1[0,2048) h2[2048,6144) h3[6144,8192) h4[8192,9216) per parity
    __shared__ __align__(16) unsigned short hall[2][9216];

    bf16x8 wreg[48];
    f32x4 bvv[6];

#define LOADW(BASE, WP, H_, CB, KC_, MT_)                                          \
    _Pragma("unroll")                                                              \
    for (int mt = 0; mt < MT_; ++mt) {                                             \
        int m = (CB) + mt * 16 + l15;                                              \
        _Pragma("unroll")                                                          \
        for (int kc = 0; kc < KC_; ++kc)                                           \
            _Pragma("unroll")                                                      \
            for (int j = 0; j < 8; ++j)                                            \
                wreg[(BASE) + kc * MT_ + mt][j] =                                  \
                    (short)f2b(WP[(kc * 32 + quad * 8 + j) * H_ + m]);             \
    }
#define LOADBF(OFF, BP, CB, MT_)                                                   \
    _Pragma("unroll")                                                              \
    for (int mt = 0; mt < MT_; ++mt) {                                             \
        float4 t4v = *reinterpret_cast<const float4*>((BP) + (CB) + mt * 16 + quad * 4); \
        bvv[(OFF) + mt][0] = t4v.x; bvv[(OFF) + mt][1] = t4v.y;                    \
        bvv[(OFF) + mt][2] = t4v.z; bvv[(OFF) + mt][3] = t4v.w;                    \
    }

    if (w < 2) {
        LOADW(0,  Wh1, 128, w * 64, 4, 4)
        LOADW(24, Wh4, 64,  w * 32, 2, 2)
        LOADW(28, Wx4, 64,  w * 32, 4, 2)
        LOADBF(0, b1, w * 64, 4)
        LOADBF(4, b4, w * 32, 2)
    } else if (w < 6) {
        __builtin_amdgcn_s_setprio(1);
        LOADW(0,  Wh2, 256, (w - 2) * 64, 8, 4)
        LOADW(32, Wx2, 256, (w - 2) * 64, 4, 4)
        LOADBF(0, b2, (w - 2) * 64, 4)
    } else {
        LOADW(0,  Wh3, 128, (w - 6) * 64, 4, 4)
        LOADW(16, Wx3, 128, (w - 6) * 64, 8, 4)
        LOADBF(0, b3, (w - 6) * 64, 4)
    }
#undef LOADW
#undef LOADBF

    for (int i = tid; i < 2 * 9216; i += 512) (&hall[0][0])[i] = 0;

    // a1 parity prefetch: aE holds even t frags, aO odd t. Per lane 2x 16B.
    bf16x8 aE[2], aO[2];
    float dacc = 0.f;
    const unsigned short* Ab =
        A1 + (size_t)s * TT * 2048 + (size_t)w * 1024 + (size_t)(quad * 16 + l15) * 16;
    if (w < 2) {
        aE[0] = *reinterpret_cast<const bf16x8*>(Ab);
        aE[1] = *reinterpret_cast<const bf16x8*>(Ab + 8);
        aO[0] = *reinterpret_cast<const bf16x8*>(Ab + 2048);
        aO[1] = *reinterpret_cast<const bf16x8*>(Ab + 2048 + 8);
    }
    __syncthreads();

    const unsigned short* aq0 = Ab + 2 * 2048;   // even prefetch target (t=2)
    const unsigned short* aq1 = Ab + 3 * 2048;   // odd (t=3)

    const int wro1 = (w * 8 + (quad >> 1)) * 128 + l15 * 8 + (quad & 1) * 4;
    const int wro4 = 8192 + (w * 4 + (quad >> 1)) * 128 + l15 * 8 + (quad & 1) * 4;
    const int wro2 = 2048 + ((w - 2) * 8 + (quad >> 1)) * 128 + l15 * 8 + (quad & 1) * 4;
    const int wro3 = 6144 + ((w - 6) * 8 + (quad >> 1)) * 128 + l15 * 8 + (quad & 1) * 4;

#define PACKMK(ACC_MT)                                                             \
    ushort2 lo = pk2(fmaxf((ACC_MT)[0], 0.f), fmaxf((ACC_MT)[1], 0.f));            \
    ushort2 hi = pk2(fmaxf((ACC_MT)[2], 0.f), fmaxf((ACC_MT)[3], 0.f));            \
    ushort4 o; o.x = lo.x; o.y = lo.y; o.z = hi.x; o.w = hi.y;

#define STEP(TAU_, RP_, WP_, AREG, APP)                                            \
    {                                                                              \
        const int tau_ = (TAU_);                                                   \
        const unsigned short* RB = &hall[RP_][0];                                  \
        unsigned short* WB = &hall[WP_][0];                                        \
        if (w < 2) {                                                               \
            const int t4_ = tau_ - 3;                                              \
            float4 wd0 = {0.f, 0.f, 0.f, 0.f}, wd1 = {0.f, 0.f, 0.f, 0.f};         \
            if ((unsigned)t4_ < TT) { /* issue Wd loads early; used in L4 tail */  \
                const float* wp_ = Wd + (size_t)t4_ * 64 + w * 32 + quad * 4;      \
                wd0 = *reinterpret_cast<const float4*>(wp_);                       \
                wd1 = *reinterpret_cast<const float4*>(wp_ + 16);                  \
            }                                                                      \
            if ((unsigned)tau_ < TT) { /* L1: h1 = relu(b1 + a1 + h1@Wh1) */       \
                f32x4 acc[4];                                                      \
                _Pragma("unroll")                                                  \
                for (int mt = 0; mt < 4; ++mt) {                                   \
                    acc[mt] = bvv[mt];                                             \
                    _Pragma("unroll")                                              \
                    for (int j = 0; j < 4; ++j)                                    \
                        acc[mt][j] += b2f(                                         \
                            (unsigned short)AREG[(mt * 4 + j) >> 3][(mt * 4 + j) & 7]); \
                }                                                                  \
                if (tau_ + 2 < TT) {                                               \
                    AREG[0] = *reinterpret_cast<const bf16x8*>(APP);               \
                    AREG[1] = *reinterpret_cast<const bf16x8*>(APP + 8);           \
                    APP += 4096;                                                   \
                }                                                                  \
                _Pragma("unroll")                                                  \
                for (int kc = 0; kc < 4; ++kc) {                                   \
                    bf16x8 af = *reinterpret_cast<const bf16x8*>(&RB[rdo + kc * 512]); \
                    _Pragma("unroll")                                              \
                    for (int mt = 0; mt < 4; ++mt)                                 \
                        acc[mt] = __builtin_amdgcn_mfma_f32_16x16x32_bf16(         \
                            wreg[kc * 4 + mt], af, acc[mt], 0, 0, 0);              \
                }                                                                  \
                _Pragma("unroll")                                                  \
                for (int mt = 0; mt < 4; ++mt) {                                   \
                    PACKMK(acc[mt])                                                \
                    *reinterpret_cast<ushort4*>(&WB[wro1 + mt * 256]) = o;         \
                }                                                                  \
            }                                                                      \
            if ((unsigned)t4_ < TT) { /* L4 + fused dense accumulate */            \
                f32x4 acc[2];                                                      \
                {                                                                  \
                    bf16x8 af0 = *reinterpret_cast<const bf16x8*>(&RB[6144 + rdo]); \
                    _Pragma("unroll")                                              \
                    for (int mt = 0; mt < 2; ++mt)                                 \
                        acc[mt] = __builtin_amdgcn_mfma_f32_16x16x32_bf16(         \
                            wreg[28 + mt], af0, bvv[4 + mt], 0, 0, 0);             \
                }                                                                  \
                _Pragma("unroll")                                                  \
                for (int kx = 1; kx < 4; ++kx) {                                   \
                    bf16x8 af = *reinterpret_cast<const bf16x8*>(&RB[6144 + rdo + kx * 512]); \
                    _Pragma("unroll")                                              \
                    for (int mt = 0; mt < 2; ++mt)                                 \
                        acc[mt] = __builtin_amdgcn_mfma_f32_16x16x32_bf16(         \
                            wreg[28 + kx * 2 + mt], af, acc[mt], 0, 0, 0);         \
                }                                                                  \
                _Pragma("unroll")                                                  \
                for (int kc = 0; kc < 2; ++kc) {                                   \
                    bf16x8 af = *reinterpret_cast<const bf16x8*>(&RB[8192 + rdo + kc * 512]); \
                    _Pragma("unroll")                                              \
                    for (int mt = 0; mt < 2; ++mt)                                 \
                        acc[mt] = __builtin_amdgcn_mfma_f32_16x16x32_bf16(         \
                            wreg[24 + kc * 2 + mt], af, acc[mt], 0, 0, 0);         \
                }                                                                  \
                _Pragma("unroll")                                                  \
                for (int mt = 0; mt < 2; ++mt) {                                   \
                    float r0 = fmaxf(acc[mt][0], 0.f), r1 = fmaxf(acc[mt][1], 0.f); \
                    float r2 = fmaxf(acc[mt][2], 0.f), r3 = fmaxf(acc[mt][3], 0.f); \
                    ushort2 lo = pk2(r0, r1), hi = pk2(r2, r3);                    \
                    ushort4 o; o.x = lo.x; o.y = lo.y; o.z = hi.x; o.w = hi.y;     \
                    *reinterpret_cast<ushort4*>(&WB[wro4 + mt * 256]) = o;         \
                    const float4 wdv = mt ? wd1 : wd0;                             \
                    dacc += r0 * wdv.x + r1 * wdv.y + r2 * wdv.z + r3 * wdv.w;     \
                }                                                                  \
            }                                                                      \
        } else if (w < 6) {                                                        \
            if ((unsigned)(tau_ - 1) < TT) { /* L2 */                              \
                f32x4 acc[4];                                                      \
                {                                                                  \
                    bf16x8 af0 = *reinterpret_cast<const bf16x8*>(&RB[rdo]);       \
                    _Pragma("unroll")                                              \
                    for (int mt = 0; mt < 4; ++mt)                                 \
                        acc[mt] = __builtin_amdgcn_mfma_f32_16x16x32_bf16(         \
                            wreg[32 + mt], af0, bvv[mt], 0, 0, 0);                 \
                }                                                                  \
                _Pragma("unroll")                                                  \
                for (int kx = 1; kx < 4; ++kx) {                                   \
                    bf16x8 af = *reinterpret_cast<const bf16x8*>(&RB[rdo + kx * 512]); \
                    _Pragma("unroll")                                              \
                    for (int mt = 0; mt < 4; ++mt)                                 \
                        acc[mt] = __builtin_amdgcn_mfma_f32_16x16x32_bf16(         \
                            wreg[32 + kx * 4 + mt], af, acc[mt], 0, 0, 0);         \
                }                                                                  \
                _Pragma("unroll")                                                  \
                for (int kc = 0; kc < 8; ++kc) {                                   \
                    bf16x8 af = *reinterpret_cast<const bf16x8*>(&RB[2048 + rdo + kc * 512]); \
                    _Pragma("unroll")                                              \
                    for (int mt = 0; mt < 4; ++mt)                                 \
                        acc[mt] = __builtin_amdgcn_mfma_f32_16x16x32_bf16(         \
                            wreg[kc * 4 + mt], af, acc[mt], 0, 0, 0);              \
                }                                                                  \
                _Pragma("unroll")                                                  \
                for (int mt = 0; mt < 4; ++mt) {                                   \
                    PACKMK(acc[mt])                                                \
                    *reinterpret_cast<ushort4*>(&WB[wro2 + mt * 256]) = o;         \
                }                                                                  \
            }                                                                      \
        } else {                                                                   \
            if ((unsigned)(tau_ - 2) < TT) { /* L3 */                              \
                f32x4 acc[4];                                                      \
                {                                                                  \
                    bf16x8 af0 = *reinterpret_cast<const bf16x8*>(&RB[2048 + rdo]); \
                    _Pragma("unroll")                                              \
                    for (int mt = 0; mt < 4; ++mt)                                 \
                        acc[mt] = __builtin_amdgcn_mfma_f32_16x16x32_bf16(         \
                            wreg[16 + mt], af0, bvv[mt], 0, 0, 0);                 \
                }                                                                  \
                _Pragma("unroll")                                                  \
                for (int kx = 1; kx < 8; ++kx) {                                   \
                    bf16x8 af = *reinterpret_cast<const bf16x8*>(&RB[2048 + rdo + kx * 512]); \
                    _Pragma("unroll")                                              \
                    for (int mt = 0; mt < 4; ++mt)                                 \
                        acc[mt] = __builtin_amdgcn_mfma_f32_16x16x32_bf16(         \
                            wreg[16 + kx * 4 + mt], af, acc[mt], 0, 0, 0);         \
                }                                                                  \
                _Pragma("unroll")                                                  \
                for (int kc = 0; kc < 4; ++kc) {                                   \
                    bf16x8 af = *reinterpret_cast<const bf16x8*>(&RB[6144 + rdo + kc * 512]); \
                    _Pragma("unroll")                                              \
                    for (int mt = 0; mt < 4; ++mt)                                 \
                        acc[mt] = __builtin_amdgcn_mfma_f32_16x16x32_bf16(         \
                            wreg[kc * 4 + mt], af, acc[mt], 0, 0, 0);              \
                }                                                                  \
                _Pragma("unroll")                                                  \
                for (int mt = 0; mt < 4; ++mt) {                                   \
                    PACKMK(acc[mt])                                                \
                    *reinterpret_cast<ushort4*>(&WB[wro3 + mt * 256]) = o;         \
                }                                                                  \
            }                                                                      \
        }                                                                          \
        __builtin_amdgcn_s_waitcnt(0xC07F);                                        \
        __builtin_amdgcn_s_barrier();                                              \
    }

#pragma unroll 1
    for (int tau = 0; tau < TT + 3; tau += 2) {
        STEP(tau, 0, 1, aE, aq0)
        STEP(tau + 1, 1, 0, aO, aq1)
    }
#undef STEP
#undef PACKMK

    // fused dense epilogue: out[s*16+b] = bd + sum_t h4[b,t,:] . Wd[t*64:]
    // lane (w,quad,l15) holds the (b=l15, k in w*32+mt*16+quad*4+j) partial;
    // 8 lanes per b. Last STEP's barrier makes hall[0] reuse safe.
    {
        float* red = reinterpret_cast<float*>(&hall[0][0]);
        if (w < 2) red[(w * 4 + quad) * 16 + l15] = dacc;
        __syncthreads();
        if (tid < 16) {
            float sum = bd[0];
#pragma unroll
            for (int j = 0; j < 8; ++j) sum += red[j * 16 + tid];
            out[s * 16 + tid] = sum;
        }
    }
}

extern "C" void kernel_launch(void* const* d_in, const int* in_sizes, int n_in,
                              void* d_out, int out_size, void* d_ws, size_t ws_size,
                              hipStream_t stream) {
    (void)in_sizes; (void)n_in; (void)out_size; (void)ws_size;
    const float* x   = (const float*)d_in[0];
    const float* Wx1 = (const float*)d_in[1];
    const float* Wh1 = (const float*)d_in[2];
    const float* b1  = (const float*)d_in[3];
    const float* Wx2 = (const float*)d_in[4];
    const float* Wh2 = (const float*)d_in[5];
    const float* b2  = (const float*)d_in[6];
    const float* Wx3 = (const float*)d_in[7];
    const float* Wh3 = (const float*)d_in[8];
    const float* b3  = (const float*)d_in[9];
    const float* Wx4 = (const float*)d_in[10];
    const float* Wh4 = (const float*)d_in[11];
    const float* b4  = (const float*)d_in[12];
    const float* Wd  = (const float*)d_in[13];
    const float* bd  = (const float*)d_in[14];
    float* out = (float*)d_out;

    unsigned short* a1 = (unsigned short*)d_ws;   // 512*256*128*2B = 33.55 MB

    xw1<<<256, 256, 0, stream>>>(x, Wx1, a1);

    rnn4<<<32, 512, 0, stream>>>(a1, Wh1, b1, Wx2, Wh2, b2,
                                 Wx3, Wh3, b3, Wx4, Wh4, b4, Wd, bd, out);
}